// Round 4
// baseline (107.302 us; speedup 1.0000x reference)
//
#include <hip/hip_runtime.h>
#include <math.h>

#define NV 8
#define NBINS 128
#define GRID 256
#define TPB 256
#define MAGIC 0x5A5A7E3Du   // != 0xAAAAAAAA poison, which is our implicit flag init

// ws layout (floats):
// [0, GRID*8)            pmin[GRID][8]
// [GRID*8, 2*GRID*8)     pmax[GRID][8]
// [2*GRID*8, +GRID)      flags[GRID] (as uint; 0xAA poison == "not ready")

__device__ __forceinline__ void quant_one(float feat, const float* __restrict__ lv,
                                          float fmin, float step,
                                          float& bin_out, float& reg_out) {
    // candidate (approximate), then exact reference fixup
    int b = (int)floorf((feat - fmin) / step);
    b = b < 0 ? 0 : (b > NBINS - 1 ? NBINS - 1 : b);
    // exact rule: largest b with rintf((lin[b]-feat)*1e6) <= 0  (diff monotone in b)
    while (b < NBINS - 1 &&
           rintf(__fmul_rn(__fsub_rn(lv[b + 1], feat), 1.0e6f)) <= 0.0f) ++b;
    while (b > 0 &&
           rintf(__fmul_rn(__fsub_rn(lv[b], feat), 1.0e6f)) > 0.0f) --b;
    const float val = lv[b];
    bin_out = (float)b;
    reg_out = __fdiv_rn(fmaxf(__fsub_rn(feat, val), 0.0f), step);
}

__global__ __launch_bounds__(TPB) void k_fused(const float* __restrict__ feats,
                                               float* __restrict__ ws,
                                               float* __restrict__ out, int n) {
    const int tid = threadIdx.x;
    const int bid = blockIdx.x;
    const int gt = bid * TPB + tid;
    const int nth = GRID * TPB;
    const int wave = tid >> 6, lane = tid & 63;

    __shared__ float swmin[4][NV], swmax[4][NV];
    __shared__ float sfmin[NV], sfmax[NV], sstep[NV];
    __shared__ float slin[NV * 129];  // +1 pad per row: bank-conflict-free

    // ---------------- phase 1: block-partial column min/max ----------------
    float lmin[NV], lmax[NV];
#pragma unroll
    for (int c = 0; c < NV; ++c) { lmin[c] = __builtin_inff(); lmax[c] = -__builtin_inff(); }

    const int n4 = n >> 2;
    const float4* f4 = (const float4*)feats;
    // quad q covers cols (4q)&7: q even -> cols 0-3, q odd -> cols 4-7.
    // grid stride nth is even, so each thread's quad parity is fixed.
    if ((gt & 1) == 0) {
        for (int q = gt; q < n4; q += nth) {
            float4 v = f4[q];
            lmin[0] = fminf(lmin[0], v.x); lmax[0] = fmaxf(lmax[0], v.x);
            lmin[1] = fminf(lmin[1], v.y); lmax[1] = fmaxf(lmax[1], v.y);
            lmin[2] = fminf(lmin[2], v.z); lmax[2] = fmaxf(lmax[2], v.z);
            lmin[3] = fminf(lmin[3], v.w); lmax[3] = fmaxf(lmax[3], v.w);
        }
    } else {
        for (int q = gt; q < n4; q += nth) {
            float4 v = f4[q];
            lmin[4] = fminf(lmin[4], v.x); lmax[4] = fmaxf(lmax[4], v.x);
            lmin[5] = fminf(lmin[5], v.y); lmax[5] = fmaxf(lmax[5], v.y);
            lmin[6] = fminf(lmin[6], v.z); lmax[6] = fmaxf(lmax[6], v.z);
            lmin[7] = fminf(lmin[7], v.w); lmax[7] = fmaxf(lmax[7], v.w);
        }
    }
    for (int i = (n4 << 2) + gt; i < n; i += nth) {   // n%4 tail
        float v = feats[i];
        int c = i & 7;
#pragma unroll
        for (int cc = 0; cc < NV; ++cc)
            if (cc == c) { lmin[cc] = fminf(lmin[cc], v); lmax[cc] = fmaxf(lmax[cc], v); }
    }
#pragma unroll
    for (int c = 0; c < NV; ++c) {
#pragma unroll
        for (int m = 32; m >= 1; m >>= 1) {
            lmin[c] = fminf(lmin[c], __shfl_xor(lmin[c], m));
            lmax[c] = fmaxf(lmax[c], __shfl_xor(lmax[c], m));
        }
    }
    if (lane == 0) {
#pragma unroll
        for (int c = 0; c < NV; ++c) { swmin[wave][c] = lmin[c]; swmax[wave][c] = lmax[c]; }
    }
    __syncthreads();
    if (tid < NV) {
        float mn = fminf(fminf(swmin[0][tid], swmin[1][tid]), fminf(swmin[2][tid], swmin[3][tid]));
        float mx = fmaxf(fmaxf(swmax[0][tid], swmax[1][tid]), fmaxf(swmax[2][tid], swmax[3][tid]));
        ws[bid * NV + tid] = mn;
        ws[GRID * NV + bid * NV + tid] = mx;
    }

    // ---------------- hand-rolled grid barrier (regular launch) ----------------
    // All 256 blocks are co-resident (256 CUs, tiny footprint). Each block:
    // drain its partials to agent-coherent point, release its flag, then every
    // thread waits on one distinct block's flag. Poison 0xAA is the "not ready"
    // state, so no separate flag init is needed.
    unsigned* flags = (unsigned*)(ws + 2 * GRID * NV);
    __threadfence();                 // agent-scope: publishes this block's partials
    __syncthreads();                 // flag store below ordered after all drains
    if (tid == 0)
        __hip_atomic_store(&flags[bid], MAGIC, __ATOMIC_RELEASE, __HIP_MEMORY_SCOPE_AGENT);
    while (__hip_atomic_load(&flags[tid], __ATOMIC_ACQUIRE, __HIP_MEMORY_SCOPE_AGENT) != MAGIC)
        __builtin_amdgcn_s_sleep(2);
    __syncthreads();

    // ---------------- phase 2a: every block reduces the 256 partials ----------------
    {
        // thread tid loads block-tid's partials with agent-scope coherent loads
        float mn[NV], mx[NV];
#pragma unroll
        for (int c = 0; c < NV; ++c) {
            mn[c] = __hip_atomic_load(&ws[tid * NV + c], __ATOMIC_RELAXED, __HIP_MEMORY_SCOPE_AGENT);
            mx[c] = __hip_atomic_load(&ws[GRID * NV + tid * NV + c], __ATOMIC_RELAXED, __HIP_MEMORY_SCOPE_AGENT);
        }
#pragma unroll
        for (int c = 0; c < NV; ++c) {
#pragma unroll
            for (int m = 32; m >= 1; m >>= 1) {
                mn[c] = fminf(mn[c], __shfl_xor(mn[c], m));
                mx[c] = fmaxf(mx[c], __shfl_xor(mx[c], m));
            }
        }
        __syncthreads();  // swmin/swmax reuse
        if (lane == 0) {
#pragma unroll
            for (int c = 0; c < NV; ++c) { swmin[wave][c] = mn[c]; swmax[wave][c] = mx[c]; }
        }
        __syncthreads();
        if (tid < NV) {
            sfmin[tid] = fminf(fminf(swmin[0][tid], swmin[1][tid]), fminf(swmin[2][tid], swmin[3][tid]));
            sfmax[tid] = fmaxf(fmaxf(swmax[0][tid], swmax[1][tid]), fmaxf(swmax[2][tid], swmax[3][tid]));
        }
        __syncthreads();
    }

    // ---------------- phase 2b: build exact lin table (bitwise == numpy) ----------------
    for (int e = tid; e < NV * NBINS; e += TPB) {
        int v = e >> 7;
        int b = e & 127;
        float fmin = sfmin[v];
        float range = __fsub_rn(sfmax[v], fmin);            // fmax - fmin
        float tb = __fdiv_rn((float)b, 127.0f);             // arange/127, correctly rounded
        slin[v * 129 + b] = __fadd_rn(fmin, __fmul_rn(range, tb));  // mul then add, NO fma
    }
    __syncthreads();
    if (tid < NV)
        sstep[tid] = __fsub_rn(slin[tid * 129 + 1], slin[tid * 129 + 0]);
    __syncthreads();

    // ---------------- phase 2c: quantize, float4 in / float4 out ----------------
    float* outr_base = out + n;
    if ((n & 3) == 0) {
        float4* outb = (float4*)out;
        float4* outr = (float4*)outr_base;
        if ((gt & 1) == 0) {
            for (int q = gt; q < n4; q += nth) {
                float4 v = f4[q];
                float4 bb, rr;
                quant_one(v.x, &slin[0 * 129], sfmin[0], sstep[0], bb.x, rr.x);
                quant_one(v.y, &slin[1 * 129], sfmin[1], sstep[1], bb.y, rr.y);
                quant_one(v.z, &slin[2 * 129], sfmin[2], sstep[2], bb.z, rr.z);
                quant_one(v.w, &slin[3 * 129], sfmin[3], sstep[3], bb.w, rr.w);
                outb[q] = bb; outr[q] = rr;
            }
        } else {
            for (int q = gt; q < n4; q += nth) {
                float4 v = f4[q];
                float4 bb, rr;
                quant_one(v.x, &slin[4 * 129], sfmin[4], sstep[4], bb.x, rr.x);
                quant_one(v.y, &slin[5 * 129], sfmin[5], sstep[5], bb.y, rr.y);
                quant_one(v.z, &slin[6 * 129], sfmin[6], sstep[6], bb.z, rr.z);
                quant_one(v.w, &slin[7 * 129], sfmin[7], sstep[7], bb.w, rr.w);
                outb[q] = bb; outr[q] = rr;
            }
        }
    } else {
        for (int i = gt; i < n; i += nth) {
            int v = i & 7;
            float bb, rr;
            quant_one(feats[i], &slin[v * 129], sfmin[v], sstep[v], bb, rr);
            out[i] = bb; outr_base[i] = rr;
        }
    }
}

extern "C" void kernel_launch(void* const* d_in, const int* in_sizes, int n_in,
                              void* d_out, int out_size, void* d_ws, size_t ws_size,
                              hipStream_t stream) {
    const float* feats = (const float*)d_in[0];
    float* ws = (float*)d_ws;
    float* out = (float*)d_out;
    int n = in_sizes[0];
    k_fused<<<GRID, TPB, 0, stream>>>(feats, ws, out, n);
}

// Round 5
// 103.211 us; speedup vs baseline: 1.0396x; 1.0396x over previous
//
#include <hip/hip_runtime.h>
#include <math.h>

#define NV 8
#define NBINS 128
#define GRID 256
#define TPB 256
#define MAGIC 0x5A5A7E3Du   // != 0xAAAAAAAA poison (and != 0), so any harness init reads "not ready"

// ws layout (floats):
// [0, GRID*8)            pmin[GRID][8]
// [GRID*8, 2*GRID*8)     pmax[GRID][8]
// [2*GRID*8, +GRID)      flags[GRID] (as uint; anything != MAGIC == "not ready")

__device__ __forceinline__ void quant_one(float feat, const float* __restrict__ lv,
                                          float fmin, float step,
                                          float& bin_out, float& reg_out) {
    // candidate (approximate), then exact reference fixup
    int b = (int)floorf((feat - fmin) / step);
    b = b < 0 ? 0 : (b > NBINS - 1 ? NBINS - 1 : b);
    // exact rule: largest b with rintf((lin[b]-feat)*1e6) <= 0  (diff monotone in b)
    while (b < NBINS - 1 &&
           rintf(__fmul_rn(__fsub_rn(lv[b + 1], feat), 1.0e6f)) <= 0.0f) ++b;
    while (b > 0 &&
           rintf(__fmul_rn(__fsub_rn(lv[b], feat), 1.0e6f)) > 0.0f) --b;
    const float val = lv[b];
    bin_out = (float)b;
    reg_out = __fdiv_rn(fmaxf(__fsub_rn(feat, val), 0.0f), step);
}

__global__ __launch_bounds__(TPB) void k_fused(const float* __restrict__ feats,
                                               float* __restrict__ ws,
                                               float* __restrict__ out, int n) {
    const int tid = threadIdx.x;
    const int bid = blockIdx.x;
    const int gt = bid * TPB + tid;
    const int nth = GRID * TPB;
    const int wave = tid >> 6, lane = tid & 63;

    __shared__ float swmin[4][NV], swmax[4][NV];
    __shared__ float sfmin[NV], sfmax[NV], sstep[NV];
    __shared__ float slin[NV * 129];  // +1 pad per row: bank-conflict-free

    // ---------------- phase 1: block-partial column min/max ----------------
    float lmin[NV], lmax[NV];
#pragma unroll
    for (int c = 0; c < NV; ++c) { lmin[c] = __builtin_inff(); lmax[c] = -__builtin_inff(); }

    const int n4 = n >> 2;
    const float4* f4 = (const float4*)feats;
    // quad q covers cols (4q)&7: q even -> cols 0-3, q odd -> cols 4-7.
    // grid stride nth is even, so each thread's quad parity is fixed.
    if ((gt & 1) == 0) {
        for (int q = gt; q < n4; q += nth) {
            float4 v = f4[q];
            lmin[0] = fminf(lmin[0], v.x); lmax[0] = fmaxf(lmax[0], v.x);
            lmin[1] = fminf(lmin[1], v.y); lmax[1] = fmaxf(lmax[1], v.y);
            lmin[2] = fminf(lmin[2], v.z); lmax[2] = fmaxf(lmax[2], v.z);
            lmin[3] = fminf(lmin[3], v.w); lmax[3] = fmaxf(lmax[3], v.w);
        }
    } else {
        for (int q = gt; q < n4; q += nth) {
            float4 v = f4[q];
            lmin[4] = fminf(lmin[4], v.x); lmax[4] = fmaxf(lmax[4], v.x);
            lmin[5] = fminf(lmin[5], v.y); lmax[5] = fmaxf(lmax[5], v.y);
            lmin[6] = fminf(lmin[6], v.z); lmax[6] = fmaxf(lmax[6], v.z);
            lmin[7] = fminf(lmin[7], v.w); lmax[7] = fmaxf(lmax[7], v.w);
        }
    }
    for (int i = (n4 << 2) + gt; i < n; i += nth) {   // n%4 tail
        float v = feats[i];
        int c = i & 7;
#pragma unroll
        for (int cc = 0; cc < NV; ++cc)
            if (cc == c) { lmin[cc] = fminf(lmin[cc], v); lmax[cc] = fmaxf(lmax[cc], v); }
    }
#pragma unroll
    for (int c = 0; c < NV; ++c) {
#pragma unroll
        for (int m = 32; m >= 1; m >>= 1) {
            lmin[c] = fminf(lmin[c], __shfl_xor(lmin[c], m));
            lmax[c] = fmaxf(lmax[c], __shfl_xor(lmax[c], m));
        }
    }
    if (lane == 0) {
#pragma unroll
        for (int c = 0; c < NV; ++c) { swmin[wave][c] = lmin[c]; swmax[wave][c] = lmax[c]; }
    }
    __syncthreads();
    if (tid < NV) {
        float mn = fminf(fminf(swmin[0][tid], swmin[1][tid]), fminf(swmin[2][tid], swmin[3][tid]));
        float mx = fmaxf(fmaxf(swmax[0][tid], swmax[1][tid]), fmaxf(swmax[2][tid], swmax[3][tid]));
        ws[bid * NV + tid] = mn;
        ws[GRID * NV + bid * NV + tid] = mx;
    }

    // ---------------- hand-rolled grid barrier (cheap spin) ----------------
    // All 256 blocks co-resident (1 block/CU, tiny footprint). Producer: drain
    // partials (__threadfence), release per-block flag. Consumer: ONLY wave 0
    // spins — lane l watches flags[4l..4l+3] with RELAXED agent loads (no
    // per-iteration cache invalidate, unlike acquire) + s_sleep backoff. A
    // single __threadfence() after the spin supplies acquire ordering.
    unsigned* flags = (unsigned*)(ws + 2 * GRID * NV);
    __threadfence();                 // publish this block's partials (agent scope)
    __syncthreads();                 // flag store ordered after all lanes' stores
    if (tid == 0)
        __hip_atomic_store(&flags[bid], MAGIC, __ATOMIC_RELEASE, __HIP_MEMORY_SCOPE_AGENT);
    if (tid < 64) {
        const int base = tid << 2;
        unsigned done = 0;
        while (done != 0xFu) {
#pragma unroll
            for (int j = 0; j < 4; ++j) {
                if (!((done >> j) & 1u)) {
                    if (__hip_atomic_load(&flags[base + j], __ATOMIC_RELAXED,
                                          __HIP_MEMORY_SCOPE_AGENT) == MAGIC)
                        done |= (1u << j);
                }
            }
            if (done != 0xFu) __builtin_amdgcn_s_sleep(8);
        }
    }
    __threadfence();                 // acquire side: discard stale cached state
    __syncthreads();

    // ---------------- phase 2a: every block reduces the 256 partials ----------------
    {
        // thread tid loads block-tid's partials with agent-scope coherent loads
        float mn[NV], mx[NV];
#pragma unroll
        for (int c = 0; c < NV; ++c) {
            mn[c] = __hip_atomic_load(&ws[tid * NV + c], __ATOMIC_RELAXED, __HIP_MEMORY_SCOPE_AGENT);
            mx[c] = __hip_atomic_load(&ws[GRID * NV + tid * NV + c], __ATOMIC_RELAXED, __HIP_MEMORY_SCOPE_AGENT);
        }
#pragma unroll
        for (int c = 0; c < NV; ++c) {
#pragma unroll
            for (int m = 32; m >= 1; m >>= 1) {
                mn[c] = fminf(mn[c], __shfl_xor(mn[c], m));
                mx[c] = fmaxf(mx[c], __shfl_xor(mx[c], m));
            }
        }
        __syncthreads();  // swmin/swmax reuse
        if (lane == 0) {
#pragma unroll
            for (int c = 0; c < NV; ++c) { swmin[wave][c] = mn[c]; swmax[wave][c] = mx[c]; }
        }
        __syncthreads();
        if (tid < NV) {
            sfmin[tid] = fminf(fminf(swmin[0][tid], swmin[1][tid]), fminf(swmin[2][tid], swmin[3][tid]));
            sfmax[tid] = fmaxf(fmaxf(swmax[0][tid], swmax[1][tid]), fmaxf(swmax[2][tid], swmax[3][tid]));
        }
        __syncthreads();
    }

    // ---------------- phase 2b: build exact lin table (bitwise == numpy) ----------------
    for (int e = tid; e < NV * NBINS; e += TPB) {
        int v = e >> 7;
        int b = e & 127;
        float fmin = sfmin[v];
        float range = __fsub_rn(sfmax[v], fmin);            // fmax - fmin
        float tb = __fdiv_rn((float)b, 127.0f);             // arange/127, correctly rounded
        slin[v * 129 + b] = __fadd_rn(fmin, __fmul_rn(range, tb));  // mul then add, NO fma
    }
    __syncthreads();
    if (tid < NV)
        sstep[tid] = __fsub_rn(slin[tid * 129 + 1], slin[tid * 129 + 0]);
    __syncthreads();

    // ---------------- phase 2c: quantize, float4 in / float4 out ----------------
    float* outr_base = out + n;
    if ((n & 3) == 0) {
        float4* outb = (float4*)out;
        float4* outr = (float4*)outr_base;
        if ((gt & 1) == 0) {
            for (int q = gt; q < n4; q += nth) {
                float4 v = f4[q];
                float4 bb, rr;
                quant_one(v.x, &slin[0 * 129], sfmin[0], sstep[0], bb.x, rr.x);
                quant_one(v.y, &slin[1 * 129], sfmin[1], sstep[1], bb.y, rr.y);
                quant_one(v.z, &slin[2 * 129], sfmin[2], sstep[2], bb.z, rr.z);
                quant_one(v.w, &slin[3 * 129], sfmin[3], sstep[3], bb.w, rr.w);
                outb[q] = bb; outr[q] = rr;
            }
        } else {
            for (int q = gt; q < n4; q += nth) {
                float4 v = f4[q];
                float4 bb, rr;
                quant_one(v.x, &slin[4 * 129], sfmin[4], sstep[4], bb.x, rr.x);
                quant_one(v.y, &slin[5 * 129], sfmin[5], sstep[5], bb.y, rr.y);
                quant_one(v.z, &slin[6 * 129], sfmin[6], sstep[6], bb.z, rr.z);
                quant_one(v.w, &slin[7 * 129], sfmin[7], sstep[7], bb.w, rr.w);
                outb[q] = bb; outr[q] = rr;
            }
        }
    } else {
        for (int i = gt; i < n; i += nth) {
            int v = i & 7;
            float bb, rr;
            quant_one(feats[i], &slin[v * 129], sfmin[v], sstep[v], bb, rr);
            out[i] = bb; outr_base[i] = rr;
        }
    }
}

extern "C" void kernel_launch(void* const* d_in, const int* in_sizes, int n_in,
                              void* d_out, int out_size, void* d_ws, size_t ws_size,
                              hipStream_t stream) {
    const float* feats = (const float*)d_in[0];
    float* ws = (float*)d_ws;
    float* out = (float*)d_out;
    int n = in_sizes[0];
    k_fused<<<GRID, TPB, 0, stream>>>(feats, ws, out, n);
}

// Round 6
// 73.203 us; speedup vs baseline: 1.4658x; 1.4099x over previous
//
#include <hip/hip_runtime.h>
#include <math.h>

#define NV 8
#define NBINS 128
#define PBLK 256   // partial-producing blocks in k_minmax (also = threads reducing them)
#define TPB 256

// ws layout (floats):
// [0, PBLK*8)            pmin[PBLK][8]
// [PBLK*8, 2*PBLK*8)     pmax[PBLK][8]

__device__ __forceinline__ void quant_one(float feat, const float* __restrict__ lv,
                                          float fmin, float step,
                                          float& bin_out, float& reg_out) {
    // candidate (approximate), then exact reference fixup
    int b = (int)floorf((feat - fmin) / step);
    b = b < 0 ? 0 : (b > NBINS - 1 ? NBINS - 1 : b);
    // exact rule: largest b with rintf((lin[b]-feat)*1e6) <= 0  (diff monotone in b)
    while (b < NBINS - 1 &&
           rintf(__fmul_rn(__fsub_rn(lv[b + 1], feat), 1.0e6f)) <= 0.0f) ++b;
    while (b > 0 &&
           rintf(__fmul_rn(__fsub_rn(lv[b], feat), 1.0e6f)) > 0.0f) --b;
    const float val = lv[b];
    bin_out = (float)b;
    reg_out = __fdiv_rn(fmaxf(__fsub_rn(feat, val), 0.0f), step);
}

// ---------------- kernel 1: per-block column min/max partials ----------------
__global__ __launch_bounds__(TPB) void k_minmax(const float* __restrict__ feats,
                                                float* __restrict__ ws, int n) {
    const int tid = threadIdx.x;
    const int bid = blockIdx.x;
    const int gt = bid * TPB + tid;
    const int nth = PBLK * TPB;
    const int wave = tid >> 6, lane = tid & 63;

    __shared__ float swmin[4][NV], swmax[4][NV];

    float lmin[NV], lmax[NV];
#pragma unroll
    for (int c = 0; c < NV; ++c) { lmin[c] = __builtin_inff(); lmax[c] = -__builtin_inff(); }

    const int n4 = n >> 2;
    const float4* f4 = (const float4*)feats;
    // quad q covers cols (4q)&7: q even -> cols 0-3, q odd -> cols 4-7.
    // grid stride nth is even, so each thread's quad parity is fixed.
    if ((gt & 1) == 0) {
        for (int q = gt; q < n4; q += nth) {
            float4 v = f4[q];
            lmin[0] = fminf(lmin[0], v.x); lmax[0] = fmaxf(lmax[0], v.x);
            lmin[1] = fminf(lmin[1], v.y); lmax[1] = fmaxf(lmax[1], v.y);
            lmin[2] = fminf(lmin[2], v.z); lmax[2] = fmaxf(lmax[2], v.z);
            lmin[3] = fminf(lmin[3], v.w); lmax[3] = fmaxf(lmax[3], v.w);
        }
    } else {
        for (int q = gt; q < n4; q += nth) {
            float4 v = f4[q];
            lmin[4] = fminf(lmin[4], v.x); lmax[4] = fmaxf(lmax[4], v.x);
            lmin[5] = fminf(lmin[5], v.y); lmax[5] = fmaxf(lmax[5], v.y);
            lmin[6] = fminf(lmin[6], v.z); lmax[6] = fmaxf(lmax[6], v.z);
            lmin[7] = fminf(lmin[7], v.w); lmax[7] = fmaxf(lmax[7], v.w);
        }
    }
    for (int i = (n4 << 2) + gt; i < n; i += nth) {   // n%4 tail
        float v = feats[i];
        int c = i & 7;
#pragma unroll
        for (int cc = 0; cc < NV; ++cc)
            if (cc == c) { lmin[cc] = fminf(lmin[cc], v); lmax[cc] = fmaxf(lmax[cc], v); }
    }
#pragma unroll
    for (int c = 0; c < NV; ++c) {
#pragma unroll
        for (int m = 32; m >= 1; m >>= 1) {
            lmin[c] = fminf(lmin[c], __shfl_xor(lmin[c], m));
            lmax[c] = fmaxf(lmax[c], __shfl_xor(lmax[c], m));
        }
    }
    if (lane == 0) {
#pragma unroll
        for (int c = 0; c < NV; ++c) { swmin[wave][c] = lmin[c]; swmax[wave][c] = lmax[c]; }
    }
    __syncthreads();
    if (tid < NV) {
        float mn = fminf(fminf(swmin[0][tid], swmin[1][tid]), fminf(swmin[2][tid], swmin[3][tid]));
        float mx = fmaxf(fmaxf(swmax[0][tid], swmax[1][tid]), fmaxf(swmax[2][tid], swmax[3][tid]));
        ws[bid * NV + tid] = mn;                    // plain stores; dispatch boundary
        ws[PBLK * NV + bid * NV + tid] = mx;        // provides cross-XCD visibility
    }
}

// ---------------- kernel 2: redundant combine + exact table + quantize ----------------
__global__ __launch_bounds__(TPB) void k_quant(const float* __restrict__ feats,
                                               const float* __restrict__ ws,
                                               float* __restrict__ out, int n) {
    const int tid = threadIdx.x;
    const int gt = blockIdx.x * TPB + tid;
    const int nth = gridDim.x * TPB;
    const int wave = tid >> 6, lane = tid & 63;

    __shared__ float swmin[4][NV], swmax[4][NV];
    __shared__ float sfmin[NV], sfmax[NV], sstep[NV];
    __shared__ float slin[NV * 129];  // +1 pad per row: bank-conflict-free

    // phase A: every block reduces the PBLK partials with plain float4 loads
    {
        const float4* p4 = (const float4*)ws;
        float4 a = p4[2 * tid], b = p4[2 * tid + 1];                         // pmin[tid][0..7]
        float4 c4 = p4[2 * PBLK + 2 * tid], d = p4[2 * PBLK + 2 * tid + 1]; // pmax[tid][0..7]
        float mn[NV] = {a.x, a.y, a.z, a.w, b.x, b.y, b.z, b.w};
        float mx[NV] = {c4.x, c4.y, c4.z, c4.w, d.x, d.y, d.z, d.w};
#pragma unroll
        for (int c = 0; c < NV; ++c) {
#pragma unroll
            for (int m = 32; m >= 1; m >>= 1) {
                mn[c] = fminf(mn[c], __shfl_xor(mn[c], m));
                mx[c] = fmaxf(mx[c], __shfl_xor(mx[c], m));
            }
        }
        if (lane == 0) {
#pragma unroll
            for (int c = 0; c < NV; ++c) { swmin[wave][c] = mn[c]; swmax[wave][c] = mx[c]; }
        }
        __syncthreads();
        if (tid < NV) {
            sfmin[tid] = fminf(fminf(swmin[0][tid], swmin[1][tid]), fminf(swmin[2][tid], swmin[3][tid]));
            sfmax[tid] = fmaxf(fmaxf(swmax[0][tid], swmax[1][tid]), fmaxf(swmax[2][tid], swmax[3][tid]));
        }
        __syncthreads();
    }

    // phase B: build exact lin table (bitwise == numpy: div, mul, add — NO fma)
    for (int e = tid; e < NV * NBINS; e += TPB) {
        int v = e >> 7;
        int b = e & 127;
        float fmin = sfmin[v];
        float range = __fsub_rn(sfmax[v], fmin);
        float tb = __fdiv_rn((float)b, 127.0f);
        slin[v * 129 + b] = __fadd_rn(fmin, __fmul_rn(range, tb));
    }
    __syncthreads();
    if (tid < NV)
        sstep[tid] = __fsub_rn(slin[tid * 129 + 1], slin[tid * 129 + 0]);
    __syncthreads();

    // phase C: quantize, float4 in / float4 out
    const int n4 = n >> 2;
    const float4* f4 = (const float4*)feats;
    float* outr_base = out + n;
    if ((n & 3) == 0) {
        float4* outb = (float4*)out;
        float4* outr = (float4*)outr_base;
        if ((gt & 1) == 0) {
            for (int q = gt; q < n4; q += nth) {
                float4 v = f4[q];
                float4 bb, rr;
                quant_one(v.x, &slin[0 * 129], sfmin[0], sstep[0], bb.x, rr.x);
                quant_one(v.y, &slin[1 * 129], sfmin[1], sstep[1], bb.y, rr.y);
                quant_one(v.z, &slin[2 * 129], sfmin[2], sstep[2], bb.z, rr.z);
                quant_one(v.w, &slin[3 * 129], sfmin[3], sstep[3], bb.w, rr.w);
                outb[q] = bb; outr[q] = rr;
            }
        } else {
            for (int q = gt; q < n4; q += nth) {
                float4 v = f4[q];
                float4 bb, rr;
                quant_one(v.x, &slin[4 * 129], sfmin[4], sstep[4], bb.x, rr.x);
                quant_one(v.y, &slin[5 * 129], sfmin[5], sstep[5], bb.y, rr.y);
                quant_one(v.z, &slin[6 * 129], sfmin[6], sstep[6], bb.z, rr.z);
                quant_one(v.w, &slin[7 * 129], sfmin[7], sstep[7], bb.w, rr.w);
                outb[q] = bb; outr[q] = rr;
            }
        }
    } else {
        for (int i = gt; i < n; i += nth) {
            int v = i & 7;
            float bb, rr;
            quant_one(feats[i], &slin[v * 129], sfmin[v], sstep[v], bb, rr);
            out[i] = bb; outr_base[i] = rr;
        }
    }
}

extern "C" void kernel_launch(void* const* d_in, const int* in_sizes, int n_in,
                              void* d_out, int out_size, void* d_ws, size_t ws_size,
                              hipStream_t stream) {
    const float* feats = (const float*)d_in[0];
    float* ws = (float*)d_ws;
    float* out = (float*)d_out;
    int n = in_sizes[0];
    k_minmax<<<PBLK, TPB, 0, stream>>>(feats, ws, n);
    k_quant<<<256, TPB, 0, stream>>>(feats, ws, out, n);
}